// Round 1
// 356.736 us; speedup vs baseline: 1.0238x; 1.0238x over previous
//
#include <hip/hip_runtime.h>
#include <math.h>

// LinkedCrossEntropy: mean over B of penalty * weight[y] * NLL
//   B = 65536, C = 1000
//   penalty = 2.0 if (argmax(y_pred[i]) != y_true[i]) && link[y_true[i]][pred] else 1.0
//   NLL = logsumexp(y_pred[i]) - y_pred[i][y_true[i]]
//
// Memory-bound: y_pred = 262 MB fp32 read once (floor ~42 us @ 6.3 TB/s).
// rocprof evidence (R2): lce_kernel absent from top-5 (all 157us 1GB poison
// fills) => kernel < 157us; dur_us 365 ~= 2x157.5 fill + ~50us kernel.
//
// This round: (a) nontemporal loads for the y_pred stream so the 4 MB link
// matrix stays L2-resident for lane0's random gather; (b) x_t extracted from
// registers (wave-uniform select + 1 shfl) instead of a dependent global
// reload -- required once y_pred bypasses L2; (c) 2-deep ping-pong prefetch
// across the statically-known 8 samples/wave to double per-wave MLP.
//
// R1 post-mortem (kept): link_matrix (jnp.bool_) is delivered as int32 --
// gather as int32, not bytes.

#define B_SAMPLES 65536
#define C_CLASSES 1000
#define C4 250                      // float4 chunks per row (1000 floats)
#define NBLOCKS 2048
#define NWAVES (NBLOCKS * 4)        // 8192 waves
#define SPW (B_SAMPLES / NWAVES)    // 8 samples per wave, exact

typedef float f4 __attribute__((ext_vector_type(4)));

__device__ __forceinline__ void load_row_nt(f4* dst, const float* __restrict__ y_pred,
                                            int s, int lane)
{
    const f4* row = (const f4*)(y_pred + (size_t)s * C_CLASSES);
    #pragma unroll
    for (int it = 0; it < 4; ++it) {
        int idx = it * 64 + lane;
        if (idx < C4) {
            dst[it] = __builtin_nontemporal_load(row + idx);
        } else {
            dst[it] = (f4){-INFINITY, -INFINITY, -INFINITY, -INFINITY};
        }
    }
}

__global__ __launch_bounds__(256) void lce_kernel(
    const float* __restrict__ y_pred,
    const int* __restrict__ y_true,
    const float* __restrict__ weight,
    const int* __restrict__ link,   // bool matrix delivered as int32
    float* __restrict__ out)
{
    const int lane = threadIdx.x & 63;
    const int wave = threadIdx.x >> 6;
    const int gwave = blockIdx.x * 4 + wave;   // < 8192

    float local = 0.0f;

    f4 va[4], vb[4];

    // ---- prologue: sample 0 row + label ----
    load_row_nt(va, y_pred, gwave, lane);
    int t_cur = y_true[gwave];

    #pragma unroll
    for (int k = 0; k < SPW; ++k) {
        const int s = gwave + k * NWAVES;

        // ---- prefetch next sample into the other buffer (static ping-pong) ----
        int t_next = 0;
        if (k + 1 < SPW) {
            f4* dst = (k & 1) ? va : vb;
            load_row_nt(dst, y_pred, s + NWAVES, lane);
            t_next = y_true[s + NWAVES];
        }
        const f4* v = (k & 1) ? vb : va;   // k is compile-time under full unroll
        const int t = t_cur;

        // ---- pass 1: per-lane max + argmax (first occurrence) ----
        float m = -INFINITY;
        int am = 0;
        #pragma unroll
        for (int it = 0; it < 4; ++it) {
            #pragma unroll
            for (int j = 0; j < 4; ++j) {
                float x = v[it][j];
                int col = (it * 64 + lane) * 4 + j;
                if (x > m) { m = x; am = col; }
            }
        }

        // ---- x_t from registers: wave-uniform t -> uniform (it_t, j_t), lane ln_t ----
        const int ct   = t >> 2;        // float4 chunk holding column t
        const int ln_t = ct & 63;       // lane that loaded it
        const int it_t = ct >> 6;       // which buffer slot
        const int j_t  = t & 3;         // element within float4
        float xt_part = 0.0f;
        #pragma unroll
        for (int it = 0; it < 4; ++it) {
            #pragma unroll
            for (int j = 0; j < 4; ++j) {
                xt_part = (it == it_t && j == j_t) ? v[it][j] : xt_part;
            }
        }

        // ---- pass 2: sum of exp(x - m); padded -inf contributes 0 ----
        float sum = 0.0f;
        #pragma unroll
        for (int it = 0; it < 4; ++it) {
            #pragma unroll
            for (int j = 0; j < 4; ++j) {
                sum += __expf(v[it][j] - m);
            }
        }

        // ---- width-64 butterfly reduce of (m, sum, am) ----
        #pragma unroll
        for (int off = 32; off > 0; off >>= 1) {
            float om  = __shfl_xor(m, off, 64);
            float os  = __shfl_xor(sum, off, 64);
            int   oam = __shfl_xor(am, off, 64);
            float M = fmaxf(m, om);
            sum = sum * __expf(m - M) + os * __expf(om - M);
            am = (om > m || (om == m && oam < am)) ? oam : am;
            m = M;
        }

        // broadcast x_t from the lane that owns it
        float xt = __shfl(xt_part, ln_t, 64);

        // ---- per-sample scalar epilogue on lane 0 ----
        if (lane == 0) {
            float nll = m + __logf(sum) - xt;
            float pen = (am != t && link[(size_t)t * C_CLASSES + am] != 0)
                            ? 2.0f : 1.0f;
            local += pen * weight[t] * nll;
        }

        t_cur = t_next;
    }

    // ---- block reduce (lane 0 of each of the 4 waves) + one atomic ----
    __shared__ float wsum[4];
    if (lane == 0) wsum[wave] = local;
    __syncthreads();
    if (threadIdx.x == 0) {
        float total = (wsum[0] + wsum[1] + wsum[2] + wsum[3]) * (1.0f / B_SAMPLES);
        atomicAdd(out, total);
    }
}

extern "C" void kernel_launch(void* const* d_in, const int* in_sizes, int n_in,
                              void* d_out, int out_size, void* d_ws, size_t ws_size,
                              hipStream_t stream) {
    const float* y_pred = (const float*)d_in[0];
    const int* y_true   = (const int*)d_in[1];
    const float* weight = (const float*)d_in[2];
    const int* link     = (const int*)d_in[3];
    float* out          = (float*)d_out;

    // Harness poisons d_out with 0xAA before every timed launch — zero it.
    hipMemsetAsync(out, 0, sizeof(float), stream);

    // 2048 blocks x 256 threads = 8192 waves -> 8 samples per wave.
    lce_kernel<<<NBLOCKS, 256, 0, stream>>>(y_pred, y_true, weight, link, out);
}